// Round 19
// baseline (112.806 us; speedup 1.0000x reference)
//
#include <hip/hip_runtime.h>
#include <hip/hip_bf16.h>

typedef unsigned short u16;
typedef unsigned int u32;
typedef __bf16 bf16x8 __attribute__((ext_vector_type(8)));
typedef float f32x4 __attribute__((ext_vector_type(4)));
typedef u32 u32x4 __attribute__((ext_vector_type(4)));

#define MFMA16(a, b, c) __builtin_amdgcn_mfma_f32_16x16x32_bf16((a), (b), (c), 0, 0, 0)

static __device__ __forceinline__ u16 f2bf(float f) {
  __hip_bfloat16 h = __float2bfloat16(f);
  return __builtin_bit_cast(u16, h);
}

static __device__ __forceinline__ u32 pack2(float a, float b) {
  return (u32)f2bf(a) | ((u32)f2bf(b) << 16);
}

static __device__ __forceinline__ bf16x8 ldbf8(const void* p) {
  return *reinterpret_cast<const bf16x8*>(p);
}

static __device__ __forceinline__ void gload_lds16(const void* g, void* l) {
  __builtin_amdgcn_global_load_lds(
      (const __attribute__((address_space(1))) u32*)g,
      (__attribute__((address_space(3))) u32*)l, 16, 0, 0);
}

// ---------------------------------------------------------------- cvt f32->bf16 (fused x, W_qkv, W_o)
__global__ void cvt_all(const float* __restrict__ x, const float* __restrict__ wq,
                        const float* __restrict__ wo, u16* __restrict__ xb,
                        u16* __restrict__ wqb, u16* __restrict__ wob) {
  int i = blockIdx.x * 256 + threadIdx.x;  // grid 4096 -> 1,048,576 threads
  const float* s;
  u16* d;
  int j;
  if (i < 524288) {
    s = x; d = xb; j = i;
  } else if (i < 917504) {
    s = wq; d = wqb; j = i - 524288;
  } else {
    s = wo; d = wob; j = i - 917504;
  }
  const float4* p = reinterpret_cast<const float4*>(s) + (size_t)j * 2;
  float4 a = p[0], b = p[1];
  uint4 o;
  o.x = (u32)f2bf(a.x) | ((u32)f2bf(a.y) << 16);
  o.y = (u32)f2bf(a.z) | ((u32)f2bf(a.w) << 16);
  o.z = (u32)f2bf(b.x) | ((u32)f2bf(b.y) << 16);
  o.w = (u32)f2bf(b.z) | ((u32)f2bf(b.w) << 16);
  reinterpret_cast<uint4*>(d)[j] = o;
}

// ---------------------------------------------------------------- GEMM C = A*B^T + bias
// 128x128 tile, BK=64, 4 waves; 3 blocks/CU; XCD-chunked block remap.
template <bool BF16OUT>
__global__ __launch_bounds__(256, 3) void gemm_bt(const u16* __restrict__ A,
                                                  const u16* __restrict__ Bm,
                                                  const float* __restrict__ bias,
                                                  void* __restrict__ Cp,
                                                  int M, int N, int K) {
  __shared__ __align__(16) char As[128 * 64 * 2];
  __shared__ __align__(16) char Bs[128 * 64 * 2];
  const int tid = threadIdx.x;
  const int lane = tid & 63;
  const int wid = tid >> 6;
  const int fr = lane & 15, fg = lane >> 4;
  // XCD-aware bijective remap (nwg % 8 == 0 for both call sites)
  const int gx = gridDim.x, nwg = gx * gridDim.y;
  const int id = blockIdx.y * gx + blockIdx.x;
  const int nid = (id & 7) * (nwg >> 3) + (id >> 3);
  const int bm = nid / gx, bn = nid % gx;
  const int wm = (wid >> 1) * 64, wn = (wid & 1) * 64;

  f32x4 acc[4][4];
#pragma unroll
  for (int i = 0; i < 4; ++i)
#pragma unroll
    for (int j = 0; j < 4; ++j) acc[i][j] = (f32x4){0.f, 0.f, 0.f, 0.f};

  const int nk = K >> 6;
  for (int kt = 0; kt < nk; ++kt) {
#pragma unroll
    for (int it = 0; it < 4; ++it) {
      int q = it * 256 + tid;
      int row = q >> 3;
      int c = (q & 7) ^ (row & 7);  // pre-swizzled source chunk
      gload_lds16(A + (size_t)(bm * 128 + row) * K + kt * 64 + c * 8, As + q * 16);
      gload_lds16(Bm + (size_t)(bn * 128 + row) * K + kt * 64 + c * 8, Bs + q * 16);
    }
    __syncthreads();
#pragma unroll
    for (int mk = 0; mk < 2; ++mk) {
      bf16x8 af[4], bfr[4];
#pragma unroll
      for (int i = 0; i < 4; ++i) {
        int row = wm + i * 16 + fr;
        af[i] = ldbf8(As + ((row * 128 + mk * 64 + fg * 16) ^ ((row & 7) << 4)));
      }
#pragma unroll
      for (int j = 0; j < 4; ++j) {
        int row = wn + j * 16 + fr;
        bfr[j] = ldbf8(Bs + ((row * 128 + mk * 64 + fg * 16) ^ ((row & 7) << 4)));
      }
#pragma unroll
      for (int i = 0; i < 4; ++i)
#pragma unroll
        for (int j = 0; j < 4; ++j) acc[i][j] = MFMA16(af[i], bfr[j], acc[i][j]);
    }
    __syncthreads();
  }

#pragma unroll
  for (int j = 0; j < 4; ++j) {
    int col = bn * 128 + wn + j * 16 + fr;
    float bv = bias[col];
#pragma unroll
    for (int i = 0; i < 4; ++i) {
#pragma unroll
      for (int r = 0; r < 4; ++r) {
        int row = bm * 128 + wm + i * 16 + fg * 4 + r;
        float v = acc[i][j][r] + bv;
        if (BF16OUT)
          ((u16*)Cp)[(size_t)row * N + col] = f2bf(v);
        else
          ((float*)Cp)[(size_t)row * N + col] = v;
      }
    }
  }
}

// ---------------------------------------------------------------- flash attention v14
// KEY-SPLIT: 512 thr = 8 waves = (qw in 0..1 q-halves) x (kw in 0..3 key-windows).
// Each wave: 64 q-rows x its 32-key window per 128-key tile -> only 4 K + 4 V
// ds_read_b128 per tile (vs 32 in v13): per-work LDS reads halve. Shuffle-free
// P via per-window logical V order: phys (b*16+fg*4+r) -> L = fg*8+b*4+r.
// End: cross-kw reduction of O (2 tp-half rounds thru 64KB smem) and l; wave
// (kw,qw) finally owns qs=kw -> balanced epilogue. No-max exp2 softmax,
// l-via-ones-MFMA, opaque addr hoisting, lgkm-only barriers, setprio kept.
__global__ __launch_bounds__(512, 2) void attn_fwd(const u16* __restrict__ qkv,
                                                   u16* __restrict__ aout) {
  // bijective remap: id = slot*8 + xcd; bh = xcd*4 + (slot>>4); qt = slot&15
  const int id = blockIdx.y * gridDim.x + blockIdx.x;  // 0..511
  const int xcd = id & 7, slot = id >> 3;
  const int bh = xcd * 4 + (slot >> 4);
  const int qt = slot & 15;
  const int b = bh >> 4, h = bh & 15;
  const int tid = threadIdx.x, lane = tid & 63, wid = tid >> 6;
  const int fr = lane & 15, fg = (lane >> 4) & 3;
  const int kw = wid & 3, qw = wid >> 2;

  // smem: [buf0 Ks 16KB][buf1 Ks 16KB][buf0 VTs 16KB][buf1 VTs 16KB] = 64KB
  __shared__ __align__(16) char smem[65536];

  const int q0 = qt * 128 + qw * 64;  // 64 q-rows per wave (4 subtiles)
  const size_t bS = (size_t)b * 2048;
  const u16* kbase = qkv + bS * 3072 + h * 192 + 64;
  const u16* vbase = qkv + bS * 3072 + h * 192 + 128;

  // ---- staging geometry (512 threads cover 128 keys of K and V) ----
  // K: thread -> key row kr = tid>>2, chunks c4 and c4+4 (16B each)
  const int kr = tid >> 2, c4 = tid & 3;
  int kwo0 = (kr * 128 + c4 * 16) ^ ((kr & 7) << 4);
  int kwo1 = (kr * 128 + (c4 + 4) * 16) ^ ((kr & 7) << 4);
  asm volatile("" : "+v"(kwo0), "+v"(kwo1));
  // V: thread -> phys key pair p2 = 2*(tid>>3), d-chunk vdc = (tid&7)*8.
  // Logical order within each 32-key window: phys b*16+fgp*4+r -> L=fgp*8+b*4+r
  const int p2 = (tid >> 3) * 2;
  const int vdc = (tid & 7) * 8;
  const int pp = p2 & 31;
  const int vl0 = (p2 & ~31) + ((pp >> 2) & 3) * 8 + ((pp >> 4) & 1) * 4 + (pp & 3);
  int wof[8];
#pragma unroll
  for (int j = 0; j < 8; ++j) {
    int d = vdc + j;
    wof[j] = 32768 + ((d * 256 + vl0 * 2) ^ ((((d & 7) ^ ((d >> 3) & 7))) << 4));
    asm volatile("" : "+v"(wof[j]));
  }
  // ---- compute-side LDS read offsets (loop-invariant, opaque) ----
  // K frag: key = kw*32 + ks*16 + fr (key&7 == fr&7); ks*2048 added outside.
  int kro[2];
#pragma unroll
  for (int mk = 0; mk < 2; ++mk) {
    kro[mk] = kw * 4096 + ((fr * 128 + mk * 64 + fg * 16) ^ ((fr & 7) << 4));
    asm volatile("" : "+v"(kro[mk]));
  }
  // V frag: d = tp*16+fr, logical keys kw*32 + fg*8 + e (inside the XOR field)
  int vadr[4];
#pragma unroll
  for (int tp = 0; tp < 4; ++tp) {
    int d = tp * 16 + fr;
    vadr[tp] =
        32768 + ((d * 256 + kw * 64 + fg * 16) ^ ((((d & 7) ^ ((d >> 3) & 7))) << 4));
    asm volatile("" : "+v"(vadr[tp]));
  }

  // Q fragments (4 q-subtiles), pre-scaled by (1/8)*log2(e) [exp2 domain]
  bf16x8 qf[4][2];
#pragma unroll
  for (int qs = 0; qs < 4; ++qs)
#pragma unroll
    for (int mk = 0; mk < 2; ++mk) {
      bf16x8 v =
          ldbf8(qkv + (bS + q0 + qs * 16 + fr) * 3072 + h * 192 + mk * 32 + fg * 8);
#pragma unroll
      for (int e = 0; e < 8; ++e) v[e] = (__bf16)((float)v[e] * 0.1803368801f);
      qf[qs][mk] = v;
    }

  // ones B-fragment for the l row-sum MFMA
  const u32 one2 = 0x3F803F80u;
  const u32x4 onev = {one2, one2, one2, one2};
  const bf16x8 onesf = __builtin_bit_cast(bf16x8, onev);
  // opaque zero C-operand for QK MFMA
  float zs = 0.f;
  asm volatile("" : "+v"(zs));
  const f32x4 zacc = {zs, zs, zs, zs};

  f32x4 oacc[4][4];  // [qs][tp] partial O over this wave's key windows
  f32x4 lacc[4];     // [qs] partial l
#pragma unroll
  for (int qs = 0; qs < 4; ++qs) {
#pragma unroll
    for (int t = 0; t < 4; ++t) oacc[qs][t] = (f32x4){0.f, 0.f, 0.f, 0.f};
    lacc[qs] = (f32x4){0.f, 0.f, 0.f, 0.f};
  }

#define LOADT(S0, K0, K1, V0, V1)                                                   \
  K0 = *reinterpret_cast<const uint4*>(kbase + (size_t)((S0) + kr) * 3072 + c4 * 8); \
  K1 = *reinterpret_cast<const uint4*>(kbase + (size_t)((S0) + kr) * 3072 +          \
                                       (c4 + 4) * 8);                                \
  V0 = *reinterpret_cast<const uint4*>(vbase + (size_t)((S0) + p2) * 3072 + vdc);    \
  V1 = *reinterpret_cast<const uint4*>(vbase + (size_t)((S0) + p2 + 1) * 3072 + vdc);

#define STAGE(BUF, K0, K1, V0, V1)                               \
  {                                                              \
    *reinterpret_cast<uint4*>(smem + (BUF)*16384 + kwo0) = K0;   \
    *reinterpret_cast<uint4*>(smem + (BUF)*16384 + kwo1) = K1;   \
    const u16* e0 = reinterpret_cast<const u16*>(&V0);           \
    const u16* e1 = reinterpret_cast<const u16*>(&V1);           \
    _Pragma("unroll") for (int j = 0; j < 8; ++j) {              \
      u32 w = (u32)e0[j] | ((u32)e1[j] << 16);                   \
      *reinterpret_cast<u32*>(smem + (BUF)*16384 + wof[j]) = w;  \
    }                                                            \
  }

// raw barrier: drain LDS ops only; global prefetch loads stay in flight
#define BAR()                                          \
  {                                                    \
    __builtin_amdgcn_sched_barrier(0);                 \
    asm volatile("s_waitcnt lgkmcnt(0)" ::: "memory"); \
    __builtin_amdgcn_s_barrier();                      \
    __builtin_amdgcn_sched_barrier(0);                 \
  }

// one 128-key tile of compute for this wave's 32-key window x 64 q-rows
#define COMPUTE(BUF)                                                           \
  {                                                                            \
    f32x4 sc[2][4];                                                            \
    __builtin_amdgcn_s_setprio(1);                                             \
    _Pragma("unroll") for (int ks = 0; ks < 2; ++ks) {                         \
      bf16x8 kf0 = ldbf8(smem + (BUF)*16384 + kro[0] + ks * 2048);             \
      bf16x8 kf1 = ldbf8(smem + (BUF)*16384 + kro[1] + ks * 2048);             \
      _Pragma("unroll") for (int qs = 0; qs < 4; ++qs) {                       \
        sc[ks][qs] = MFMA16(kf0, qf[qs][0], zacc);                             \
        sc[ks][qs] = MFMA16(kf1, qf[qs][1], sc[ks][qs]);                       \
      }                                                                        \
    }                                                                          \
    __builtin_amdgcn_s_setprio(0);                                             \
    bf16x8 pa[4];                                                              \
    _Pragma("unroll") for (int qs = 0; qs < 4; ++qs) {                         \
      u32x4 pk;                                                                \
      pk.x = pack2(__builtin_amdgcn_exp2f(sc[0][qs][0]),                       \
                   __builtin_amdgcn_exp2f(sc[0][qs][1]));                      \
      pk.y = pack2(__builtin_amdgcn_exp2f(sc[0][qs][2]),                       \
                   __builtin_amdgcn_exp2f(sc[0][qs][3]));                      \
      pk.z = pack2(__builtin_amdgcn_exp2f(sc[1][qs][0]),                       \
                   __builtin_amdgcn_exp2f(sc[1][qs][1]));                      \
      pk.w = pack2(__builtin_amdgcn_exp2f(sc[1][qs][2]),                       \
                   __builtin_amdgcn_exp2f(sc[1][qs][3]));                      \
      pa[qs] = __builtin_bit_cast(bf16x8, pk);                                 \
    }                                                                          \
    __builtin_amdgcn_s_setprio(1);                                             \
    _Pragma("unroll") for (int qs = 0; qs < 4; ++qs) lacc[qs] =                \
        MFMA16(pa[qs], onesf, lacc[qs]);                                       \
    _Pragma("unroll") for (int tp = 0; tp < 4; ++tp) {                         \
      bf16x8 vf = ldbf8(smem + (BUF)*16384 + vadr[tp]);                        \
      _Pragma("unroll") for (int qs = 0; qs < 4; ++qs) oacc[qs][tp] =          \
          MFMA16(pa[qs], vf, oacc[qs][tp]);                                    \
    }                                                                          \
    __builtin_amdgcn_s_setprio(0);                                             \
  }

  uint4 ka0, ka1, va0, va1;
  uint4 kb0, kb1, vb0, vb1;
  // prologue: tile0 -> A -> buf0; tile1 -> B; buf0 ready after BAR
  LOADT(0, ka0, ka1, va0, va1);
  STAGE(0, ka0, ka1, va0, va1);
  LOADT(128, kb0, kb1, vb0, vb1);
  BAR();
  for (int kv = 0; kv < 16; kv += 2) {
    // phase A: prefetch kv+2 -> A; stage tile kv+1 (B) -> buf1; compute tile kv (buf0)
    {
      int s0n = (kv + 2 < 16) ? (kv + 2) * 128 : 0;  // tail: harmless reload
      LOADT(s0n, ka0, ka1, va0, va1);
    }
    STAGE(1, kb0, kb1, vb0, vb1);
    COMPUTE(0);
    BAR();
    // phase B: prefetch kv+3 -> B; stage tile kv+2 (A) -> buf0; compute tile kv+1 (buf1)
    {
      int s0n = (kv + 3 < 16) ? (kv + 3) * 128 : 128;  // tail: harmless reload
      LOADT(s0n, kb0, kb1, vb0, vb1);
    }
    STAGE(0, ka0, ka1, va0, va1);
    COMPUTE(1);
    BAR();
  }
#undef LOADT
#undef STAGE
#undef COMPUTE

  // ---- cross-kw reduction (smem is free after the final BAR) ----
  // Select own-qs (qs == kw) into named regs via compare chain (no dyn idx).
  f32x4 fin[4];
  f32x4 lfin;
#pragma unroll
  for (int tp = 0; tp < 4; ++tp) fin[tp] = oacc[0][tp];
  lfin = lacc[0];
#pragma unroll
  for (int qs = 1; qs < 4; ++qs) {
    bool own = (qs == kw);
#pragma unroll
    for (int tp = 0; tp < 4; ++tp) fin[tp] = own ? oacc[qs][tp] : fin[tp];
    lfin = own ? lacc[qs] : lfin;
  }
  const int lofs = lane * 16;
  // O: two rounds over tp-halves; 64 slots x 1KB = 64KB exactly.
#pragma unroll
  for (int rr = 0; rr < 2; ++rr) {
#pragma unroll
    for (int qs = 0; qs < 4; ++qs)
#pragma unroll
      for (int tpo = 0; tpo < 2; ++tpo)
        *reinterpret_cast<f32x4*>(
            smem + (((qw * 4 + qs) * 4 + kw) * 2 + tpo) * 1024 + lofs) =
            oacc[qs][rr * 2 + tpo];
    BAR();
#pragma unroll
    for (int w2 = 0; w2 < 4; ++w2) {
      if (w2 != kw) {
#pragma unroll
        for (int tpo = 0; tpo < 2; ++tpo)
          fin[rr * 2 + tpo] += *reinterpret_cast<const f32x4*>(
              smem + (((qw * 4 + kw) * 4 + w2) * 2 + tpo) * 1024 + lofs);
      }
    }
    BAR();
  }
  // l: 32 slots x 1KB = 32KB
#pragma unroll
  for (int qs = 0; qs < 4; ++qs)
    *reinterpret_cast<f32x4*>(smem + ((qw * 4 + qs) * 4 + kw) * 1024 + lofs) =
        lacc[qs];
  BAR();
#pragma unroll
  for (int w2 = 0; w2 < 4; ++w2) {
    if (w2 != kw) {
      lfin += *reinterpret_cast<const f32x4*>(
          smem + ((qw * 4 + kw) * 4 + w2) * 1024 + lofs);
    }
  }
#undef BAR

  // ---- epilogue: wave owns qs = kw -> rows q0 + kw*16 + fg*4 + r ----
  {
    float invb[4];
#pragma unroll
    for (int r = 0; r < 4; ++r) invb[r] = 1.f / lfin[r];
#pragma unroll
    for (int tp = 0; tp < 4; ++tp) {
#pragma unroll
      for (int r = 0; r < 4; ++r) {
        int row = q0 + kw * 16 + fg * 4 + r;
        aout[(bS + row) * 1024 + h * 64 + tp * 16 + fr] =
            f2bf(fin[tp][r] * invb[r]);
      }
    }
  }
}

// ---------------------------------------------------------------- launch
extern "C" void kernel_launch(void* const* d_in, const int* in_sizes, int n_in,
                              void* d_out, int out_size, void* d_ws, size_t ws_size,
                              hipStream_t stream) {
  const float* x = (const float*)d_in[0];
  const float* Wqkv = (const float*)d_in[1];
  const float* bqkv = (const float*)d_in[2];
  const float* Wo = (const float*)d_in[3];
  const float* bo = (const float*)d_in[4];
  float* out = (float*)d_out;
  char* ws = (char*)d_ws;

  u16* xb = (u16*)(ws);                       //  8,388,608  x bf16 [4096,1024]
  u16* wqb = (u16*)(ws + 8388608);            //  6,291,456  W_qkv bf16 [3072,1024]
  u16* wob = (u16*)(ws + 14680064);           //  2,097,152  W_o bf16 [1024,1024]
  u16* qkvb = (u16*)(ws + 16777216);          // 25,165,824  qkv bf16 [4096,3072]
  u16* attb = (u16*)(ws + 41943040);          //  8,388,608  attn out bf16 [4096,1024]

  cvt_all<<<4096, 256, 0, stream>>>(x, Wqkv, Wo, xb, wqb, wob);

  gemm_bt<true><<<dim3(24, 32), 256, 0, stream>>>(xb, wqb, bqkv, qkvb, 4096, 3072, 1024);
  attn_fwd<<<dim3(16, 32), 512, 0, stream>>>(qkvb, attb);
  gemm_bt<false><<<dim3(8, 32), 256, 0, stream>>>(attb, wob, bo, out, 4096, 1024, 1024);
}

// Round 20
// 103.374 us; speedup vs baseline: 1.0912x; 1.0912x over previous
//
#include <hip/hip_runtime.h>
#include <hip/hip_bf16.h>

typedef unsigned short u16;
typedef unsigned int u32;
typedef __bf16 bf16x8 __attribute__((ext_vector_type(8)));
typedef float f32x4 __attribute__((ext_vector_type(4)));
typedef u32 u32x4 __attribute__((ext_vector_type(4)));

#define MFMA16(a, b, c) __builtin_amdgcn_mfma_f32_16x16x32_bf16((a), (b), (c), 0, 0, 0)

static __device__ __forceinline__ u16 f2bf(float f) {
  __hip_bfloat16 h = __float2bfloat16(f);
  return __builtin_bit_cast(u16, h);
}

static __device__ __forceinline__ u32 pack2(float a, float b) {
  return (u32)f2bf(a) | ((u32)f2bf(b) << 16);
}

static __device__ __forceinline__ bf16x8 ldbf8(const void* p) {
  return *reinterpret_cast<const bf16x8*>(p);
}

static __device__ __forceinline__ void gload_lds16(const void* g, void* l) {
  __builtin_amdgcn_global_load_lds(
      (const __attribute__((address_space(1))) u32*)g,
      (__attribute__((address_space(3))) u32*)l, 16, 0, 0);
}

// ---------------------------------------------------------------- cvt f32->bf16 (fused x, W_qkv, W_o)
__global__ void cvt_all(const float* __restrict__ x, const float* __restrict__ wq,
                        const float* __restrict__ wo, u16* __restrict__ xb,
                        u16* __restrict__ wqb, u16* __restrict__ wob) {
  int i = blockIdx.x * 256 + threadIdx.x;  // grid 4096 -> 1,048,576 threads
  const float* s;
  u16* d;
  int j;
  if (i < 524288) {
    s = x; d = xb; j = i;
  } else if (i < 917504) {
    s = wq; d = wqb; j = i - 524288;
  } else {
    s = wo; d = wob; j = i - 917504;
  }
  const float4* p = reinterpret_cast<const float4*>(s) + (size_t)j * 2;
  float4 a = p[0], b = p[1];
  uint4 o;
  o.x = (u32)f2bf(a.x) | ((u32)f2bf(a.y) << 16);
  o.y = (u32)f2bf(a.z) | ((u32)f2bf(a.w) << 16);
  o.z = (u32)f2bf(b.x) | ((u32)f2bf(b.y) << 16);
  o.w = (u32)f2bf(b.z) | ((u32)f2bf(b.w) << 16);
  reinterpret_cast<uint4*>(d)[j] = o;
}

// ---------------------------------------------------------------- GEMM C = A*B^T + bias
// 128x128 tile, BK=64, 4 waves; 3 blocks/CU; XCD-chunked block remap.
template <bool BF16OUT>
__global__ __launch_bounds__(256, 3) void gemm_bt(const u16* __restrict__ A,
                                                  const u16* __restrict__ Bm,
                                                  const float* __restrict__ bias,
                                                  void* __restrict__ Cp,
                                                  int M, int N, int K) {
  __shared__ __align__(16) char As[128 * 64 * 2];
  __shared__ __align__(16) char Bs[128 * 64 * 2];
  const int tid = threadIdx.x;
  const int lane = tid & 63;
  const int wid = tid >> 6;
  const int fr = lane & 15, fg = lane >> 4;
  // XCD-aware bijective remap (nwg % 8 == 0 for both call sites)
  const int gx = gridDim.x, nwg = gx * gridDim.y;
  const int id = blockIdx.y * gx + blockIdx.x;
  const int nid = (id & 7) * (nwg >> 3) + (id >> 3);
  const int bm = nid / gx, bn = nid % gx;
  const int wm = (wid >> 1) * 64, wn = (wid & 1) * 64;

  f32x4 acc[4][4];
#pragma unroll
  for (int i = 0; i < 4; ++i)
#pragma unroll
    for (int j = 0; j < 4; ++j) acc[i][j] = (f32x4){0.f, 0.f, 0.f, 0.f};

  const int nk = K >> 6;
  for (int kt = 0; kt < nk; ++kt) {
#pragma unroll
    for (int it = 0; it < 4; ++it) {
      int q = it * 256 + tid;
      int row = q >> 3;
      int c = (q & 7) ^ (row & 7);  // pre-swizzled source chunk
      gload_lds16(A + (size_t)(bm * 128 + row) * K + kt * 64 + c * 8, As + q * 16);
      gload_lds16(Bm + (size_t)(bn * 128 + row) * K + kt * 64 + c * 8, Bs + q * 16);
    }
    __syncthreads();
#pragma unroll
    for (int mk = 0; mk < 2; ++mk) {
      bf16x8 af[4], bfr[4];
#pragma unroll
      for (int i = 0; i < 4; ++i) {
        int row = wm + i * 16 + fr;
        af[i] = ldbf8(As + ((row * 128 + mk * 64 + fg * 16) ^ ((row & 7) << 4)));
      }
#pragma unroll
      for (int j = 0; j < 4; ++j) {
        int row = wn + j * 16 + fr;
        bfr[j] = ldbf8(Bs + ((row * 128 + mk * 64 + fg * 16) ^ ((row & 7) << 4)));
      }
#pragma unroll
      for (int i = 0; i < 4; ++i)
#pragma unroll
        for (int j = 0; j < 4; ++j) acc[i][j] = MFMA16(af[i], bfr[j], acc[i][j]);
    }
    __syncthreads();
  }

#pragma unroll
  for (int j = 0; j < 4; ++j) {
    int col = bn * 128 + wn + j * 16 + fr;
    float bv = bias[col];
#pragma unroll
    for (int i = 0; i < 4; ++i) {
#pragma unroll
      for (int r = 0; r < 4; ++r) {
        int row = bm * 128 + wm + i * 16 + fg * 4 + r;
        float v = acc[i][j][r] + bv;
        if (BF16OUT)
          ((u16*)Cp)[(size_t)row * N + col] = f2bf(v);
        else
          ((float*)Cp)[(size_t)row * N + col] = v;
      }
    }
  }
}

// ---------------------------------------------------------------- GEMM 64x128 tile (fp32 out)
// For O-proj: grid (N/128, M/64) = 512 blocks -> 2 blocks/CU (vs 1 at 128^2).
// Direct restriction of gemm_bt: 4 waves of 32x64 output, acc[2][4].
__global__ __launch_bounds__(256, 2) void gemm_bt64(const u16* __restrict__ A,
                                                    const u16* __restrict__ Bm,
                                                    const float* __restrict__ bias,
                                                    float* __restrict__ Cp,
                                                    int M, int N, int K) {
  __shared__ __align__(16) char As[64 * 64 * 2];
  __shared__ __align__(16) char Bs[128 * 64 * 2];
  const int tid = threadIdx.x;
  const int lane = tid & 63;
  const int wid = tid >> 6;
  const int fr = lane & 15, fg = lane >> 4;
  const int gx = gridDim.x, nwg = gx * gridDim.y;
  const int id = blockIdx.y * gx + blockIdx.x;
  const int nid = (id & 7) * (nwg >> 3) + (id >> 3);
  const int bm = nid / gx, bn = nid % gx;
  const int wm = (wid >> 1) * 32, wn = (wid & 1) * 64;

  f32x4 acc[2][4];
#pragma unroll
  for (int i = 0; i < 2; ++i)
#pragma unroll
    for (int j = 0; j < 4; ++j) acc[i][j] = (f32x4){0.f, 0.f, 0.f, 0.f};

  const int nk = K >> 6;
  for (int kt = 0; kt < nk; ++kt) {
#pragma unroll
    for (int it = 0; it < 2; ++it) {  // A: 512 chunks
      int q = it * 256 + tid;
      int row = q >> 3;
      int c = (q & 7) ^ (row & 7);
      gload_lds16(A + (size_t)(bm * 64 + row) * K + kt * 64 + c * 8, As + q * 16);
    }
#pragma unroll
    for (int it = 0; it < 4; ++it) {  // B: 1024 chunks
      int q = it * 256 + tid;
      int row = q >> 3;
      int c = (q & 7) ^ (row & 7);
      gload_lds16(Bm + (size_t)(bn * 128 + row) * K + kt * 64 + c * 8, Bs + q * 16);
    }
    __syncthreads();
#pragma unroll
    for (int mk = 0; mk < 2; ++mk) {
      bf16x8 af[2], bfr[4];
#pragma unroll
      for (int i = 0; i < 2; ++i) {
        int row = wm + i * 16 + fr;
        af[i] = ldbf8(As + ((row * 128 + mk * 64 + fg * 16) ^ ((row & 7) << 4)));
      }
#pragma unroll
      for (int j = 0; j < 4; ++j) {
        int row = wn + j * 16 + fr;
        bfr[j] = ldbf8(Bs + ((row * 128 + mk * 64 + fg * 16) ^ ((row & 7) << 4)));
      }
#pragma unroll
      for (int i = 0; i < 2; ++i)
#pragma unroll
        for (int j = 0; j < 4; ++j) acc[i][j] = MFMA16(af[i], bfr[j], acc[i][j]);
    }
    __syncthreads();
  }

#pragma unroll
  for (int j = 0; j < 4; ++j) {
    int col = bn * 128 + wn + j * 16 + fr;
    float bv = bias[col];
#pragma unroll
    for (int i = 0; i < 2; ++i) {
#pragma unroll
      for (int r = 0; r < 4; ++r) {
        int row = bm * 64 + wm + i * 16 + fg * 4 + r;
        Cp[(size_t)row * N + col] = acc[i][j][r] + bv;
      }
    }
  }
}

// ---------------------------------------------------------------- flash attention v13 (R18-verified, 52.1us)
// 4 waves x 32 q-rows, 128-key dbuf tiles, stage-overlap, XCD remap, no-max
// exp2 softmax, l-via-MFMA, opaque hoisting, lgkm-only barriers, setprio,
// SHUFFLE-FREE PV via logical V key order phys 32m+16u+4g+e -> L 32m+8g+4u+e.
__global__ __launch_bounds__(256, 2) void attn_fwd(const u16* __restrict__ qkv,
                                                   u16* __restrict__ aout) {
  const int id = blockIdx.y * gridDim.x + blockIdx.x;  // 0..511
  const int xcd = id & 7, slot = id >> 3;
  const int bh = xcd * 4 + (slot >> 4);
  const int qt = slot & 15;
  const int b = bh >> 4, h = bh & 15;
  const int tid = threadIdx.x, lane = tid & 63, wid = tid >> 6;
  const int fr = lane & 15, fg = (lane >> 4) & 3;

  __shared__ __align__(16) char Ks[2][2][64 * 128];   // [buf][sub] swizzled [key][d]
  __shared__ __align__(16) char VTs[2][2][64 * 128];  // [buf][sub] swizzled [d][lkey]

  const int q0 = qt * 128 + wid * 32;  // 32 q-rows per wave
  const size_t bS = (size_t)b * 2048;
  const u16* kbase = qkv + bS * 3072 + h * 192 + 64;
  const u16* vbase = qkv + bS * 3072 + h * 192 + 128;

  const int krow0 = tid >> 3, krow1 = 32 + (tid >> 3);
  const int kcol = (tid & 7) * 8;
  int kw0 = (krow0 * 128 + (tid & 7) * 16) ^ ((krow0 & 7) << 4);
  int kw1 = (krow1 * 128 + (tid & 7) * 16) ^ ((krow1 & 7) << 4);
  asm volatile("" : "+v"(kw0), "+v"(kw1));
  const int vs2 = (tid >> 3) * 2;
  const int vdc = (tid & 7) * 8;
  const int vl0 = 32 * (vs2 >> 5) + 8 * ((vs2 >> 2) & 3) + 4 * ((vs2 >> 4) & 1) +
                  (vs2 & 3);  // logical slot (even)
  int wof[8];
#pragma unroll
  for (int j = 0; j < 8; ++j) {
    int d = vdc + j;
    wof[j] = ((d * 128 + vl0 * 2) ^ ((((d & 7) ^ ((d >> 3) & 7))) << 4));
    asm volatile("" : "+v"(wof[j]));
  }
  int kro[2];
#pragma unroll
  for (int mk = 0; mk < 2; ++mk) {
    kro[mk] = ((fr * 128 + mk * 64 + fg * 16) ^ ((fr & 7) << 4));
    asm volatile("" : "+v"(kro[mk]));
  }
  int vadr[4][2];
#pragma unroll
  for (int tp = 0; tp < 4; ++tp)
#pragma unroll
    for (int mk = 0; mk < 2; ++mk) {
      int d = tp * 16 + fr;
      int swz = (((d & 7) ^ ((d >> 3) & 7)) << 4);
      vadr[tp][mk] = ((d * 128 + mk * 64 + fg * 16) ^ swz);
      asm volatile("" : "+v"(vadr[tp][mk]));
    }

  bf16x8 qf[2][2];
#pragma unroll
  for (int qs = 0; qs < 2; ++qs)
#pragma unroll
    for (int mk = 0; mk < 2; ++mk) {
      bf16x8 v =
          ldbf8(qkv + (bS + q0 + qs * 16 + fr) * 3072 + h * 192 + mk * 32 + fg * 8);
#pragma unroll
      for (int e = 0; e < 8; ++e) v[e] = (__bf16)((float)v[e] * 0.1803368801f);
      qf[qs][mk] = v;
    }

  const u32 one2 = 0x3F803F80u;
  const u32x4 onev = {one2, one2, one2, one2};
  const bf16x8 onesf = __builtin_bit_cast(bf16x8, onev);
  float zs = 0.f;
  asm volatile("" : "+v"(zs));
  const f32x4 zacc = {zs, zs, zs, zs};

  f32x4 oacc0[4], oacc1[4];
#pragma unroll
  for (int t = 0; t < 4; ++t) {
    oacc0[t] = (f32x4){0.f, 0.f, 0.f, 0.f};
    oacc1[t] = (f32x4){0.f, 0.f, 0.f, 0.f};
  }
  f32x4 lacc0 = (f32x4){0.f, 0.f, 0.f, 0.f};
  f32x4 lacc1 = (f32x4){0.f, 0.f, 0.f, 0.f};

#define LOADT(S0, K0, K1, K2, K3, V0, V1, V2, V3)                                         \
  K0 = *reinterpret_cast<const uint4*>(kbase + (size_t)((S0) + krow0) * 3072 + kcol);      \
  K1 = *reinterpret_cast<const uint4*>(kbase + (size_t)((S0) + krow1) * 3072 + kcol);      \
  K2 = *reinterpret_cast<const uint4*>(kbase + (size_t)((S0) + 64 + krow0) * 3072 + kcol); \
  K3 = *reinterpret_cast<const uint4*>(kbase + (size_t)((S0) + 64 + krow1) * 3072 + kcol); \
  V0 = *reinterpret_cast<const uint4*>(vbase + (size_t)((S0) + vs2) * 3072 + vdc);         \
  V1 = *reinterpret_cast<const uint4*>(vbase + (size_t)((S0) + vs2 + 1) * 3072 + vdc);     \
  V2 = *reinterpret_cast<const uint4*>(vbase + (size_t)((S0) + 64 + vs2) * 3072 + vdc);    \
  V3 = *reinterpret_cast<const uint4*>(vbase + (size_t)((S0) + 64 + vs2 + 1) * 3072 + vdc);

#define STAGEV1(VTP, V0, V1)                           \
  {                                                    \
    const u16* e0 = reinterpret_cast<const u16*>(&V0); \
    const u16* e1 = reinterpret_cast<const u16*>(&V1); \
    _Pragma("unroll") for (int j = 0; j < 8; ++j) {    \
      u32 w = (u32)e0[j] | ((u32)e1[j] << 16);         \
      *reinterpret_cast<u32*>((VTP) + wof[j]) = w;     \
    }                                                  \
  }

#define STAGE(BUF, K0, K1, K2, K3, V0, V1, V2, V3)        \
  {                                                       \
    *reinterpret_cast<uint4*>(Ks[BUF][0] + kw0) = K0;     \
    *reinterpret_cast<uint4*>(Ks[BUF][0] + kw1) = K1;     \
    *reinterpret_cast<uint4*>(Ks[BUF][1] + kw0) = K2;     \
    *reinterpret_cast<uint4*>(Ks[BUF][1] + kw1) = K3;     \
    STAGEV1(VTs[BUF][0], V0, V1);                         \
    STAGEV1(VTs[BUF][1], V2, V3);                         \
  }

#define BAR()                                          \
  {                                                    \
    __builtin_amdgcn_sched_barrier(0);                 \
    asm volatile("s_waitcnt lgkmcnt(0)" ::: "memory"); \
    __builtin_amdgcn_s_barrier();                      \
    __builtin_amdgcn_sched_barrier(0);                 \
  }

#define COMPUTE1(KSP, VTP)                                                     \
  {                                                                            \
    f32x4 sc0[4], sc1[4];                                                      \
    __builtin_amdgcn_s_setprio(1);                                             \
    _Pragma("unroll") for (int t = 0; t < 4; ++t) {                            \
      bf16x8 kf0 = ldbf8((KSP) + kro[0] + t * 2048);                           \
      bf16x8 kf1 = ldbf8((KSP) + kro[1] + t * 2048);                           \
      sc0[t] = MFMA16(kf0, qf[0][0], zacc);                                    \
      sc0[t] = MFMA16(kf1, qf[0][1], sc0[t]);                                  \
      sc1[t] = MFMA16(kf0, qf[1][0], zacc);                                    \
      sc1[t] = MFMA16(kf1, qf[1][1], sc1[t]);                                  \
    }                                                                          \
    __builtin_amdgcn_s_setprio(0);                                             \
    u32 Wp0[2][4], Wp1[2][4];                                                  \
    _Pragma("unroll") for (int t = 0; t < 4; ++t) {                            \
      Wp0[0][t] = pack2(__builtin_amdgcn_exp2f(sc0[t][0]),                     \
                        __builtin_amdgcn_exp2f(sc0[t][1]));                    \
      Wp0[1][t] = pack2(__builtin_amdgcn_exp2f(sc0[t][2]),                     \
                        __builtin_amdgcn_exp2f(sc0[t][3]));                    \
      Wp1[0][t] = pack2(__builtin_amdgcn_exp2f(sc1[t][0]),                     \
                        __builtin_amdgcn_exp2f(sc1[t][1]));                    \
      Wp1[1][t] = pack2(__builtin_amdgcn_exp2f(sc1[t][2]),                     \
                        __builtin_amdgcn_exp2f(sc1[t][3]));                    \
    }                                                                          \
    _Pragma("unroll") for (int mk = 0; mk < 2; ++mk) {                         \
      u32x4 pk0, pk1;                                                          \
      pk0.x = Wp0[0][2 * mk];                                                  \
      pk0.y = Wp0[1][2 * mk];                                                  \
      pk0.z = Wp0[0][2 * mk + 1];                                              \
      pk0.w = Wp0[1][2 * mk + 1];                                              \
      pk1.x = Wp1[0][2 * mk];                                                  \
      pk1.y = Wp1[1][2 * mk];                                                  \
      pk1.z = Wp1[0][2 * mk + 1];                                              \
      pk1.w = Wp1[1][2 * mk + 1];                                              \
      bf16x8 pa0 = __builtin_bit_cast(bf16x8, pk0);                            \
      bf16x8 pa1 = __builtin_bit_cast(bf16x8, pk1);                            \
      __builtin_amdgcn_s_setprio(1);                                           \
      lacc0 = MFMA16(pa0, onesf, lacc0);                                       \
      lacc1 = MFMA16(pa1, onesf, lacc1);                                       \
      _Pragma("unroll") for (int tp = 0; tp < 4; ++tp) {                       \
        bf16x8 vf = ldbf8((VTP) + vadr[tp][mk]);                               \
        oacc0[tp] = MFMA16(pa0, vf, oacc0[tp]);                                \
        oacc1[tp] = MFMA16(pa1, vf, oacc1[tp]);                                \
      }                                                                        \
      __builtin_amdgcn_s_setprio(0);                                           \
    }                                                                          \
  }

#define COMPUTE(BUF)                   \
  {                                    \
    COMPUTE1(Ks[BUF][0], VTs[BUF][0]); \
    COMPUTE1(Ks[BUF][1], VTs[BUF][1]); \
  }

  uint4 ka0, ka1, ka2, ka3, va0, va1, va2, va3;
  uint4 kb0, kb1, kb2, kb3, vb0, vb1, vb2, vb3;
  LOADT(0, ka0, ka1, ka2, ka3, va0, va1, va2, va3);
  STAGE(0, ka0, ka1, ka2, ka3, va0, va1, va2, va3);
  LOADT(128, kb0, kb1, kb2, kb3, vb0, vb1, vb2, vb3);
  BAR();
  for (int kv = 0; kv < 16; kv += 2) {
    {
      int s0n = (kv + 2 < 16) ? (kv + 2) * 128 : 0;
      LOADT(s0n, ka0, ka1, ka2, ka3, va0, va1, va2, va3);
    }
    STAGE(1, kb0, kb1, kb2, kb3, vb0, vb1, vb2, vb3);
    COMPUTE(0);
    BAR();
    {
      int s0n = (kv + 3 < 16) ? (kv + 3) * 128 : 128;
      LOADT(s0n, kb0, kb1, kb2, kb3, vb0, vb1, vb2, vb3);
    }
    STAGE(0, ka0, ka1, ka2, ka3, va0, va1, va2, va3);
    COMPUTE(1);
    BAR();
  }
#undef LOADT
#undef STAGEV1
#undef STAGE
#undef BAR
#undef COMPUTE1
#undef COMPUTE

  {
    float invb0[4], invb1[4];
#pragma unroll
    for (int r = 0; r < 4; ++r) {
      invb0[r] = 1.f / lacc0[r];
      invb1[r] = 1.f / lacc1[r];
    }
#pragma unroll
    for (int tp = 0; tp < 4; ++tp) {
#pragma unroll
      for (int r = 0; r < 4; ++r) {
        int row0 = q0 + fg * 4 + r;
        aout[(bS + row0) * 1024 + h * 64 + tp * 16 + fr] =
            f2bf(oacc0[tp][r] * invb0[r]);
        int row1 = q0 + 16 + fg * 4 + r;
        aout[(bS + row1) * 1024 + h * 64 + tp * 16 + fr] =
            f2bf(oacc1[tp][r] * invb1[r]);
      }
    }
  }
}

// ---------------------------------------------------------------- launch
extern "C" void kernel_launch(void* const* d_in, const int* in_sizes, int n_in,
                              void* d_out, int out_size, void* d_ws, size_t ws_size,
                              hipStream_t stream) {
  const float* x = (const float*)d_in[0];
  const float* Wqkv = (const float*)d_in[1];
  const float* bqkv = (const float*)d_in[2];
  const float* Wo = (const float*)d_in[3];
  const float* bo = (const float*)d_in[4];
  float* out = (float*)d_out;
  char* ws = (char*)d_ws;

  u16* xb = (u16*)(ws);                       //  8,388,608  x bf16 [4096,1024]
  u16* wqb = (u16*)(ws + 8388608);            //  6,291,456  W_qkv bf16 [3072,1024]
  u16* wob = (u16*)(ws + 14680064);           //  2,097,152  W_o bf16 [1024,1024]
  u16* qkvb = (u16*)(ws + 16777216);          // 25,165,824  qkv bf16 [4096,3072]
  u16* attb = (u16*)(ws + 41943040);          //  8,388,608  attn out bf16 [4096,1024]

  cvt_all<<<4096, 256, 0, stream>>>(x, Wqkv, Wo, xb, wqb, wob);

  gemm_bt<true><<<dim3(24, 32), 256, 0, stream>>>(xb, wqb, bqkv, qkvb, 4096, 3072, 1024);
  attn_fwd<<<dim3(16, 32), 256, 0, stream>>>(qkvb, attb);
  gemm_bt64<<<dim3(8, 64), 256, 0, stream>>>(attb, wob, bo, out, 4096, 1024, 1024);
}

// Round 21
// 102.726 us; speedup vs baseline: 1.0981x; 1.0063x over previous
//
#include <hip/hip_runtime.h>
#include <hip/hip_bf16.h>

typedef unsigned short u16;
typedef unsigned int u32;
typedef __bf16 bf16x8 __attribute__((ext_vector_type(8)));
typedef float f32x4 __attribute__((ext_vector_type(4)));
typedef u32 u32x4 __attribute__((ext_vector_type(4)));

#define MFMA16(a, b, c) __builtin_amdgcn_mfma_f32_16x16x32_bf16((a), (b), (c), 0, 0, 0)

static __device__ __forceinline__ u16 f2bf(float f) {
  __hip_bfloat16 h = __float2bfloat16(f);
  return __builtin_bit_cast(u16, h);
}

static __device__ __forceinline__ u32 pack2(float a, float b) {
  return (u32)f2bf(a) | ((u32)f2bf(b) << 16);
}

static __device__ __forceinline__ bf16x8 ldbf8(const void* p) {
  return *reinterpret_cast<const bf16x8*>(p);
}

static __device__ __forceinline__ void gload_lds16(const void* g, void* l) {
  __builtin_amdgcn_global_load_lds(
      (const __attribute__((address_space(1))) u32*)g,
      (__attribute__((address_space(3))) u32*)l, 16, 0, 0);
}

// ---------------------------------------------------------------- cvt f32->bf16 (fused x, W_qkv, W_o)
__global__ void cvt_all(const float* __restrict__ x, const float* __restrict__ wq,
                        const float* __restrict__ wo, u16* __restrict__ xb,
                        u16* __restrict__ wqb, u16* __restrict__ wob) {
  int i = blockIdx.x * 256 + threadIdx.x;  // grid 4096 -> 1,048,576 threads
  const float* s;
  u16* d;
  int j;
  if (i < 524288) {
    s = x; d = xb; j = i;
  } else if (i < 917504) {
    s = wq; d = wqb; j = i - 524288;
  } else {
    s = wo; d = wob; j = i - 917504;
  }
  const float4* p = reinterpret_cast<const float4*>(s) + (size_t)j * 2;
  float4 a = p[0], b = p[1];
  uint4 o;
  o.x = (u32)f2bf(a.x) | ((u32)f2bf(a.y) << 16);
  o.y = (u32)f2bf(a.z) | ((u32)f2bf(a.w) << 16);
  o.z = (u32)f2bf(b.x) | ((u32)f2bf(b.y) << 16);
  o.w = (u32)f2bf(b.z) | ((u32)f2bf(b.w) << 16);
  reinterpret_cast<uint4*>(d)[j] = o;
}

// ---------------------------------------------------------------- GEMM C = A*B^T + bias
// 128x128 tile, BK=64, 4 waves; 3 blocks/CU; XCD-chunked block remap.
template <bool BF16OUT>
__global__ __launch_bounds__(256, 3) void gemm_bt(const u16* __restrict__ A,
                                                  const u16* __restrict__ Bm,
                                                  const float* __restrict__ bias,
                                                  void* __restrict__ Cp,
                                                  int M, int N, int K) {
  __shared__ __align__(16) char As[128 * 64 * 2];
  __shared__ __align__(16) char Bs[128 * 64 * 2];
  const int tid = threadIdx.x;
  const int lane = tid & 63;
  const int wid = tid >> 6;
  const int fr = lane & 15, fg = lane >> 4;
  // XCD-aware bijective remap (nwg % 8 == 0 for both call sites)
  const int gx = gridDim.x, nwg = gx * gridDim.y;
  const int id = blockIdx.y * gx + blockIdx.x;
  const int nid = (id & 7) * (nwg >> 3) + (id >> 3);
  const int bm = nid / gx, bn = nid % gx;
  const int wm = (wid >> 1) * 64, wn = (wid & 1) * 64;

  f32x4 acc[4][4];
#pragma unroll
  for (int i = 0; i < 4; ++i)
#pragma unroll
    for (int j = 0; j < 4; ++j) acc[i][j] = (f32x4){0.f, 0.f, 0.f, 0.f};

  const int nk = K >> 6;
  for (int kt = 0; kt < nk; ++kt) {
#pragma unroll
    for (int it = 0; it < 4; ++it) {
      int q = it * 256 + tid;
      int row = q >> 3;
      int c = (q & 7) ^ (row & 7);  // pre-swizzled source chunk
      gload_lds16(A + (size_t)(bm * 128 + row) * K + kt * 64 + c * 8, As + q * 16);
      gload_lds16(Bm + (size_t)(bn * 128 + row) * K + kt * 64 + c * 8, Bs + q * 16);
    }
    __syncthreads();
#pragma unroll
    for (int mk = 0; mk < 2; ++mk) {
      bf16x8 af[4], bfr[4];
#pragma unroll
      for (int i = 0; i < 4; ++i) {
        int row = wm + i * 16 + fr;
        af[i] = ldbf8(As + ((row * 128 + mk * 64 + fg * 16) ^ ((row & 7) << 4)));
      }
#pragma unroll
      for (int j = 0; j < 4; ++j) {
        int row = wn + j * 16 + fr;
        bfr[j] = ldbf8(Bs + ((row * 128 + mk * 64 + fg * 16) ^ ((row & 7) << 4)));
      }
#pragma unroll
      for (int i = 0; i < 4; ++i)
#pragma unroll
        for (int j = 0; j < 4; ++j) acc[i][j] = MFMA16(af[i], bfr[j], acc[i][j]);
    }
    __syncthreads();
  }

#pragma unroll
  for (int j = 0; j < 4; ++j) {
    int col = bn * 128 + wn + j * 16 + fr;
    float bv = bias[col];
#pragma unroll
    for (int i = 0; i < 4; ++i) {
#pragma unroll
      for (int r = 0; r < 4; ++r) {
        int row = bm * 128 + wm + i * 16 + fg * 4 + r;
        float v = acc[i][j][r] + bv;
        if (BF16OUT)
          ((u16*)Cp)[(size_t)row * N + col] = f2bf(v);
        else
          ((float*)Cp)[(size_t)row * N + col] = v;
      }
    }
  }
}

// ---------------------------------------------------------------- GEMM 64x128 tile (fp32 out)
__global__ __launch_bounds__(256, 2) void gemm_bt64(const u16* __restrict__ A,
                                                    const u16* __restrict__ Bm,
                                                    const float* __restrict__ bias,
                                                    float* __restrict__ Cp,
                                                    int M, int N, int K) {
  __shared__ __align__(16) char As[64 * 64 * 2];
  __shared__ __align__(16) char Bs[128 * 64 * 2];
  const int tid = threadIdx.x;
  const int lane = tid & 63;
  const int wid = tid >> 6;
  const int fr = lane & 15, fg = lane >> 4;
  const int gx = gridDim.x, nwg = gx * gridDim.y;
  const int id = blockIdx.y * gx + blockIdx.x;
  const int nid = (id & 7) * (nwg >> 3) + (id >> 3);
  const int bm = nid / gx, bn = nid % gx;
  const int wm = (wid >> 1) * 32, wn = (wid & 1) * 64;

  f32x4 acc[2][4];
#pragma unroll
  for (int i = 0; i < 2; ++i)
#pragma unroll
    for (int j = 0; j < 4; ++j) acc[i][j] = (f32x4){0.f, 0.f, 0.f, 0.f};

  const int nk = K >> 6;
  for (int kt = 0; kt < nk; ++kt) {
#pragma unroll
    for (int it = 0; it < 2; ++it) {  // A: 512 chunks
      int q = it * 256 + tid;
      int row = q >> 3;
      int c = (q & 7) ^ (row & 7);
      gload_lds16(A + (size_t)(bm * 64 + row) * K + kt * 64 + c * 8, As + q * 16);
    }
#pragma unroll
    for (int it = 0; it < 4; ++it) {  // B: 1024 chunks
      int q = it * 256 + tid;
      int row = q >> 3;
      int c = (q & 7) ^ (row & 7);
      gload_lds16(Bm + (size_t)(bn * 128 + row) * K + kt * 64 + c * 8, Bs + q * 16);
    }
    __syncthreads();
#pragma unroll
    for (int mk = 0; mk < 2; ++mk) {
      bf16x8 af[2], bfr[4];
#pragma unroll
      for (int i = 0; i < 2; ++i) {
        int row = wm + i * 16 + fr;
        af[i] = ldbf8(As + ((row * 128 + mk * 64 + fg * 16) ^ ((row & 7) << 4)));
      }
#pragma unroll
      for (int j = 0; j < 4; ++j) {
        int row = wn + j * 16 + fr;
        bfr[j] = ldbf8(Bs + ((row * 128 + mk * 64 + fg * 16) ^ ((row & 7) << 4)));
      }
#pragma unroll
      for (int i = 0; i < 2; ++i)
#pragma unroll
        for (int j = 0; j < 4; ++j) acc[i][j] = MFMA16(af[i], bfr[j], acc[i][j]);
    }
    __syncthreads();
  }

#pragma unroll
  for (int j = 0; j < 4; ++j) {
    int col = bn * 128 + wn + j * 16 + fr;
    float bv = bias[col];
#pragma unroll
    for (int i = 0; i < 2; ++i) {
#pragma unroll
      for (int r = 0; r < 4; ++r) {
        int row = bm * 64 + wm + i * 16 + fg * 4 + r;
        Cp[(size_t)row * N + col] = acc[i][j][r] + bv;
      }
    }
  }
}

// ---------------------------------------------------------------- flash attention v15
// R18 structure + K staged via global_load_lds DIRECT (pre-swizzled source,
// linear dest == swizzled layout; read-side kro XOR unchanged) — deletes all
// K reg-loads and K ds_writes. Barrier becomes counted: per tile issue 4 K
// gloads (t+1) FIRST, sched_barrier, then 4 V reg-loads (t+2); at the barrier
// s_waitcnt vmcnt(4) lgkmcnt(0) waits K(t+1) (older) while V(t+2) stays in
// flight. Buffer writes begin only after the barrier retiring their readers.
__global__ __launch_bounds__(256, 2) void attn_fwd(const u16* __restrict__ qkv,
                                                   u16* __restrict__ aout) {
  const int id = blockIdx.y * gridDim.x + blockIdx.x;  // 0..511
  const int xcd = id & 7, slot = id >> 3;
  const int bh = xcd * 4 + (slot >> 4);
  const int qt = slot & 15;
  const int b = bh >> 4, h = bh & 15;
  const int tid = threadIdx.x, lane = tid & 63, wid = tid >> 6;
  const int fr = lane & 15, fg = (lane >> 4) & 3;

  __shared__ __align__(16) char Ks[2][2][64 * 128];   // [buf][sub] swizzled [key][d]
  __shared__ __align__(16) char VTs[2][2][64 * 128];  // [buf][sub] swizzled [d][lkey]

  const int q0 = qt * 128 + wid * 32;  // 32 q-rows per wave
  const size_t bS = (size_t)b * 2048;
  const u16* kbase = qkv + bS * 3072 + h * 192 + 64;
  const u16* vbase = qkv + bS * 3072 + h * 192 + 128;

  // V staging geometry (loop-invariant)
  const int vs2 = (tid >> 3) * 2;
  const int vdc = (tid & 7) * 8;
  const int vl0 = 32 * (vs2 >> 5) + 8 * ((vs2 >> 2) & 3) + 4 * ((vs2 >> 4) & 1) +
                  (vs2 & 3);  // shuffle-free logical slot (even)
  int wof[8];
#pragma unroll
  for (int j = 0; j < 8; ++j) {
    int d = vdc + j;
    wof[j] = ((d * 128 + vl0 * 2) ^ ((((d & 7) ^ ((d >> 3) & 7))) << 4));
    asm volatile("" : "+v"(wof[j]));
  }
  int kro[2];
#pragma unroll
  for (int mk = 0; mk < 2; ++mk) {
    kro[mk] = ((fr * 128 + mk * 64 + fg * 16) ^ ((fr & 7) << 4));
    asm volatile("" : "+v"(kro[mk]));
  }
  int vadr[4][2];
#pragma unroll
  for (int tp = 0; tp < 4; ++tp)
#pragma unroll
    for (int mk = 0; mk < 2; ++mk) {
      int d = tp * 16 + fr;
      int swz = (((d & 7) ^ ((d >> 3) & 7)) << 4);
      vadr[tp][mk] = ((d * 128 + mk * 64 + fg * 16) ^ swz);
      asm volatile("" : "+v"(vadr[tp][mk]));
    }

  bf16x8 qf[2][2];
#pragma unroll
  for (int qs = 0; qs < 2; ++qs)
#pragma unroll
    for (int mk = 0; mk < 2; ++mk) {
      bf16x8 v =
          ldbf8(qkv + (bS + q0 + qs * 16 + fr) * 3072 + h * 192 + mk * 32 + fg * 8);
#pragma unroll
      for (int e = 0; e < 8; ++e) v[e] = (__bf16)((float)v[e] * 0.1803368801f);
      qf[qs][mk] = v;
    }

  const u32 one2 = 0x3F803F80u;
  const u32x4 onev = {one2, one2, one2, one2};
  const bf16x8 onesf = __builtin_bit_cast(bf16x8, onev);
  float zs = 0.f;
  asm volatile("" : "+v"(zs));
  const f32x4 zacc = {zs, zs, zs, zs};

  f32x4 oacc0[4], oacc1[4];
#pragma unroll
  for (int t = 0; t < 4; ++t) {
    oacc0[t] = (f32x4){0.f, 0.f, 0.f, 0.f};
    oacc1[t] = (f32x4){0.f, 0.f, 0.f, 0.f};
  }
  f32x4 lacc0 = (f32x4){0.f, 0.f, 0.f, 0.f};
  f32x4 lacc1 = (f32x4){0.f, 0.f, 0.f, 0.f};

// K tile (128 keys) -> Ks[BUF] via 4 gload_lds/thread (pre-swizzled source)
#define KISSUE(S0, BUF)                                                        \
  _Pragma("unroll") for (int it = 0; it < 2; ++it) {                           \
    int q = it * 256 + tid;                                                    \
    int row = q >> 3;                                                          \
    int c = (q & 7) ^ (row & 7);                                               \
    gload_lds16(kbase + (size_t)((S0) + row) * 3072 + c * 8,                   \
                Ks[BUF][0] + q * 16);                                          \
    gload_lds16(kbase + (size_t)((S0) + 64 + row) * 3072 + c * 8,              \
                Ks[BUF][1] + q * 16);                                          \
  }

#define LOADV(S0, V0, V1, V2, V3)                                                  \
  V0 = *reinterpret_cast<const uint4*>(vbase + (size_t)((S0) + vs2) * 3072 + vdc); \
  V1 = *reinterpret_cast<const uint4*>(vbase + (size_t)((S0) + vs2 + 1) * 3072 + vdc); \
  V2 = *reinterpret_cast<const uint4*>(vbase + (size_t)((S0) + 64 + vs2) * 3072 + vdc); \
  V3 = *reinterpret_cast<const uint4*>(vbase + (size_t)((S0) + 64 + vs2 + 1) * 3072 + vdc);

#define STAGEV1(VTP, V0, V1)                           \
  {                                                    \
    const u16* e0 = reinterpret_cast<const u16*>(&V0); \
    const u16* e1 = reinterpret_cast<const u16*>(&V1); \
    _Pragma("unroll") for (int j = 0; j < 8; ++j) {    \
      u32 w = (u32)e0[j] | ((u32)e1[j] << 16);         \
      *reinterpret_cast<u32*>((VTP) + wof[j]) = w;     \
    }                                                  \
  }

#define STAGEV(BUF, V0, V1, V2, V3)   \
  {                                   \
    STAGEV1(VTs[BUF][0], V0, V1);     \
    STAGEV1(VTs[BUF][1], V2, V3);     \
  }

// counted barrier: K(t+1) gloads (4, older) drained; V(t+2) loads (4) fly on
#define BARC()                                                   \
  {                                                              \
    __builtin_amdgcn_sched_barrier(0);                           \
    asm volatile("s_waitcnt vmcnt(4) lgkmcnt(0)" ::: "memory");  \
    __builtin_amdgcn_s_barrier();                                \
    __builtin_amdgcn_sched_barrier(0);                           \
  }

#define COMPUTE1(KSP, VTP)                                                     \
  {                                                                            \
    f32x4 sc0[4], sc1[4];                                                      \
    __builtin_amdgcn_s_setprio(1);                                             \
    _Pragma("unroll") for (int t = 0; t < 4; ++t) {                            \
      bf16x8 kf0 = ldbf8((KSP) + kro[0] + t * 2048);                           \
      bf16x8 kf1 = ldbf8((KSP) + kro[1] + t * 2048);                           \
      sc0[t] = MFMA16(kf0, qf[0][0], zacc);                                    \
      sc0[t] = MFMA16(kf1, qf[0][1], sc0[t]);                                  \
      sc1[t] = MFMA16(kf0, qf[1][0], zacc);                                    \
      sc1[t] = MFMA16(kf1, qf[1][1], sc1[t]);                                  \
    }                                                                          \
    __builtin_amdgcn_s_setprio(0);                                             \
    u32 Wp0[2][4], Wp1[2][4];                                                  \
    _Pragma("unroll") for (int t = 0; t < 4; ++t) {                            \
      Wp0[0][t] = pack2(__builtin_amdgcn_exp2f(sc0[t][0]),                     \
                        __builtin_amdgcn_exp2f(sc0[t][1]));                    \
      Wp0[1][t] = pack2(__builtin_amdgcn_exp2f(sc0[t][2]),                     \
                        __builtin_amdgcn_exp2f(sc0[t][3]));                    \
      Wp1[0][t] = pack2(__builtin_amdgcn_exp2f(sc1[t][0]),                     \
                        __builtin_amdgcn_exp2f(sc1[t][1]));                    \
      Wp1[1][t] = pack2(__builtin_amdgcn_exp2f(sc1[t][2]),                     \
                        __builtin_amdgcn_exp2f(sc1[t][3]));                    \
    }                                                                          \
    _Pragma("unroll") for (int mk = 0; mk < 2; ++mk) {                         \
      u32x4 pk0, pk1;                                                          \
      pk0.x = Wp0[0][2 * mk];                                                  \
      pk0.y = Wp0[1][2 * mk];                                                  \
      pk0.z = Wp0[0][2 * mk + 1];                                              \
      pk0.w = Wp0[1][2 * mk + 1];                                              \
      pk1.x = Wp1[0][2 * mk];                                                  \
      pk1.y = Wp1[1][2 * mk];                                                  \
      pk1.z = Wp1[0][2 * mk + 1];                                              \
      pk1.w = Wp1[1][2 * mk + 1];                                              \
      bf16x8 pa0 = __builtin_bit_cast(bf16x8, pk0);                            \
      bf16x8 pa1 = __builtin_bit_cast(bf16x8, pk1);                            \
      __builtin_amdgcn_s_setprio(1);                                           \
      lacc0 = MFMA16(pa0, onesf, lacc0);                                       \
      lacc1 = MFMA16(pa1, onesf, lacc1);                                       \
      _Pragma("unroll") for (int tp = 0; tp < 4; ++tp) {                       \
        bf16x8 vf = ldbf8((VTP) + vadr[tp][mk]);                               \
        oacc0[tp] = MFMA16(pa0, vf, oacc0[tp]);                                \
        oacc1[tp] = MFMA16(pa1, vf, oacc1[tp]);                                \
      }                                                                        \
      __builtin_amdgcn_s_setprio(0);                                           \
    }                                                                          \
  }

#define COMPUTE(BUF)                   \
  {                                    \
    COMPUTE1(Ks[BUF][0], VTs[BUF][0]); \
    COMPUTE1(Ks[BUF][1], VTs[BUF][1]); \
  }

  uint4 va0, va1, va2, va3;
  uint4 vb0, vb1, vb2, vb3;
  // prologue: K(0)->Ks[0] (gload); V(0)->va->VTs[0]; V(1)->vb; barrier.
  // STAGEV's wait on va (ops after K(0)) drains K(0) for this wave; barrier
  // publishes residency. At BARC outstanding = vb(4) only.
  KISSUE(0, 0);
  __builtin_amdgcn_sched_barrier(0);
  LOADV(0, va0, va1, va2, va3);
  STAGEV(0, va0, va1, va2, va3);
  LOADV(128, vb0, vb1, vb2, vb3);
  BARC();
  for (int kv = 0; kv < 16; kv += 2) {
    // phase A (tile kv, buf0): K(kv+1)->Ks[1]; V(kv+2)->va; V(kv+1)->VTs[1]
    {
      int sk = (kv + 1 < 16) ? (kv + 1) * 128 : 0;  // tail: harmless write
      KISSUE(sk, 1);
    }
    __builtin_amdgcn_sched_barrier(0);
    {
      int sv = (kv + 2 < 16) ? (kv + 2) * 128 : 0;  // tail: harmless load
      LOADV(sv, va0, va1, va2, va3);
    }
    STAGEV(1, vb0, vb1, vb2, vb3);
    COMPUTE(0);
    BARC();
    // phase B (tile kv+1, buf1): K(kv+2)->Ks[0]; V(kv+3)->vb; V(kv+2)->VTs[0]
    {
      int sk = (kv + 2 < 16) ? (kv + 2) * 128 : 0;
      KISSUE(sk, 0);
    }
    __builtin_amdgcn_sched_barrier(0);
    {
      int sv = (kv + 3 < 16) ? (kv + 3) * 128 : 128;
      LOADV(sv, vb0, vb1, vb2, vb3);
    }
    STAGEV(0, va0, va1, va2, va3);
    COMPUTE(1);
    BARC();
  }
#undef KISSUE
#undef LOADV
#undef STAGEV1
#undef STAGEV
#undef BARC
#undef COMPUTE1
#undef COMPUTE

  {
    float invb0[4], invb1[4];
#pragma unroll
    for (int r = 0; r < 4; ++r) {
      invb0[r] = 1.f / lacc0[r];
      invb1[r] = 1.f / lacc1[r];
    }
#pragma unroll
    for (int tp = 0; tp < 4; ++tp) {
#pragma unroll
      for (int r = 0; r < 4; ++r) {
        int row0 = q0 + fg * 4 + r;
        aout[(bS + row0) * 1024 + h * 64 + tp * 16 + fr] =
            f2bf(oacc0[tp][r] * invb0[r]);
        int row1 = q0 + 16 + fg * 4 + r;
        aout[(bS + row1) * 1024 + h * 64 + tp * 16 + fr] =
            f2bf(oacc1[tp][r] * invb1[r]);
      }
    }
  }
}

// ---------------------------------------------------------------- launch
extern "C" void kernel_launch(void* const* d_in, const int* in_sizes, int n_in,
                              void* d_out, int out_size, void* d_ws, size_t ws_size,
                              hipStream_t stream) {
  const float* x = (const float*)d_in[0];
  const float* Wqkv = (const float*)d_in[1];
  const float* bqkv = (const float*)d_in[2];
  const float* Wo = (const float*)d_in[3];
  const float* bo = (const float*)d_in[4];
  float* out = (float*)d_out;
  char* ws = (char*)d_ws;

  u16* xb = (u16*)(ws);                       //  8,388,608  x bf16 [4096,1024]
  u16* wqb = (u16*)(ws + 8388608);            //  6,291,456  W_qkv bf16 [3072,1024]
  u16* wob = (u16*)(ws + 14680064);           //  2,097,152  W_o bf16 [1024,1024]
  u16* qkvb = (u16*)(ws + 16777216);          // 25,165,824  qkv bf16 [4096,3072]
  u16* attb = (u16*)(ws + 41943040);          //  8,388,608  attn out bf16 [4096,1024]

  cvt_all<<<4096, 256, 0, stream>>>(x, Wqkv, Wo, xb, wqb, wob);

  gemm_bt<true><<<dim3(24, 32), 256, 0, stream>>>(xb, wqb, bqkv, qkvb, 4096, 3072, 1024);
  attn_fwd<<<dim3(16, 32), 256, 0, stream>>>(qkvb, attb);
  gemm_bt64<<<dim3(8, 64), 256, 0, stream>>>(attb, wob, bo, out, 4096, 1024, 1024);
}